// Round 19
// baseline (78.424 us; speedup 1.0000x reference)
//
#include <hip/hip_runtime.h>

#define NC 14
#define DIM 96
#define NV (DIM*DIM*DIM)       // 884736
#define NV4 (NV/4)             // 221184
// padded mask volume: [ph 98][pw 98][pd 112], voxel (h,w,d) -> (h+1, w+1, d+8)
#define WS2 112
#define HS2 (112*98)           // 10976
#define PADV (112*98*98)       // 1075648 elements per batch
#define HALO_UINTS (4 * (HS2 / 2))   // 4 halo slabs (2 batches x {ph=0, ph=97}) = 21952

typedef float f4 __attribute__((ext_vector_type(4)));

// ---- Kernel A: fused argmax + (w,d) 3x3 window-OR, half-slice per block ----
// 384 blocks = 2 batches x 96 h-slices x 2 row-halves. outputs_T uses CACHED
// loads (L3-resident across replays; R17's NT variant regressed 6->17us).
// Halo-slab zeroing is DISTRIBUTED across all blocks (R18 concentrated it in
// 8 blocks -> stragglers, +8us). Block 0 zeroes the 4KB accumulator.
__global__ void __launch_bounds__(256)
argmax_or_kernel(const float* __restrict__ outT, unsigned short* __restrict__ wm,
                 float* __restrict__ acc) {
    if (blockIdx.x == 0 && threadIdx.x < 64) acc[threadIdx.x * 16] = 0.f;

    // distributed h-halo zero: 21952 uints over 384 blocks = 58/block
    {
        int u = blockIdx.x * 58 + threadIdx.x;
        if (threadIdx.x < 58 && u < HALO_UINTS) {
            int slab = u / (HS2 / 2);
            int rem = u - slab * (HS2 / 2);
            int bb = slab >> 1;
            int pph = (slab & 1) ? 97 : 0;
            ((unsigned*)(wm + (size_t)bb * PADV + pph * HS2))[rem] = 0u;
        }
    }

    const int half = blockIdx.x & 1;                // row-half of the slice
    const int b = (blockIdx.x >> 1) & 1;
    const int ph = (blockIdx.x >> 2) + 1;           // 1..96
    const int h = ph - 1;
    const int r0 = half * 48;                       // pw = r0 + lr

    __shared__ unsigned short tile[50][WS2];        // 11,200 B
    for (int i = threadIdx.x; i < 50 * WS2 / 2; i += 256)
        ((unsigned*)tile)[i] = 0u;                  // halo rows/cols stay 0
    __syncthreads();

    // argmax for valid rows: half=0 -> lr 1..49 (pw 1..49), half=1 -> lr 0..48
    {
        const int lr0 = (half == 0) ? 1 : 0;
        const float* base = outT + (size_t)b * NC * NV + (size_t)h * (DIM * DIM);
        for (int i = threadIdx.x; i < 49 * 24; i += 256) {
            int lr = lr0 + i / 24;
            int d = (i % 24) * 4;
            int w = r0 + lr - 1;                    // global w = pw-1
            const float* po = base + w * DIM + d;
            f4 best = *(const f4*)po;
            int b0 = 0, b1 = 0, b2 = 0, b3 = 0;
#pragma unroll
            for (int c = 1; c < NC; ++c) {
                f4 v = *(const f4*)(po + (size_t)c * NV);
                if (v.x > best.x) { best.x = v.x; b0 = c; }
                if (v.y > best.y) { best.y = v.y; b1 = c; }
                if (v.z > best.z) { best.z = v.z; b2 = c; }
                if (v.w > best.w) { best.w = v.w; b3 = c; }
            }
            ushort4 bits;
            bits.x = (unsigned short)(1u << b0);
            bits.y = (unsigned short)(1u << b1);
            bits.z = (unsigned short)(1u << b2);
            bits.w = (unsigned short)(1u << b3);
            *(ushort4*)&tile[lr][8 + d] = bits;
        }
    }
    __syncthreads();

    // 3x3 (w,d) window-OR: 48 output rows (local 1..48) x 12 chunks of 8
    unsigned short* dst = wm + (size_t)b * PADV + ph * HS2;
    for (int i = threadIdx.x; i < 48 * 12; i += 256) {
        int lr = 1 + i / 12;
        int pd0 = 8 + (i % 12) * 8;
        uint4 A = *(const uint4*)&tile[lr - 1][pd0];
        uint4 B = *(const uint4*)&tile[lr][pd0];
        uint4 C = *(const uint4*)&tile[lr + 1][pd0];
        unsigned lft = (unsigned)tile[lr - 1][pd0 - 1] | (unsigned)tile[lr][pd0 - 1] |
                       (unsigned)tile[lr + 1][pd0 - 1];
        unsigned rgt = (unsigned)tile[lr - 1][pd0 + 8] | (unsigned)tile[lr][pd0 + 8] |
                       (unsigned)tile[lr + 1][pd0 + 8];
        uint4 W;
        W.x = A.x | B.x | C.x;
        W.y = A.y | B.y | C.y;
        W.z = A.z | B.z | C.z;
        W.w = A.w | B.w | C.w;
        unsigned x[10];
        x[0] = lft;
        x[1] = W.x & 0xFFFFu; x[2] = W.x >> 16;
        x[3] = W.y & 0xFFFFu; x[4] = W.y >> 16;
        x[5] = W.z & 0xFFFFu; x[6] = W.z >> 16;
        x[7] = W.w & 0xFFFFu; x[8] = W.w >> 16;
        x[9] = rgt;
        unsigned r[8];
#pragma unroll
        for (int j = 0; j < 8; ++j) r[j] = x[j] | x[j + 1] | x[j + 2];
        uint4 out;
        out.x = r[0] | (r[1] << 16);
        out.y = r[2] | (r[3] << 16);
        out.z = r[4] | (r[5] << 16);
        out.w = r[6] | (r[7] << 16);
        *(uint4*)(dst + (r0 + lr) * WS2 + pd0) = out;
    }
}

// ---- Kernel B: h-OR + KL + num/cnt accumulation, 4 voxels/thread ----
// CACHE PARTITION: outputs_T + preds_T L3-resident (cached); preds_S (99MB)
// NON-TEMPORAL. Natural register pressure only (R8/R15: forced wave minimums
// spill, 2x slower). Halo slabs pre-zeroed -> unconditional m0/m2 loads.
// pk tail: 1 rcp + 1 log per voxel (R17: kl 68 -> ~62us).
__global__ void __launch_bounds__(256)
boundary_kl_kernel(const float* __restrict__ pS, const float* __restrict__ pT,
                   const unsigned short* __restrict__ wm,
                   float* __restrict__ acc) {
    const int b = blockIdx.x & 1;
    int tid4 = (blockIdx.x >> 1) * 256 + threadIdx.x;    // < NV4 exactly
    int v4 = tid4 * 4;
    int d = v4 % DIM;                                    // multiple of 4
    int t1 = v4 / DIM;
    int w = t1 % DIM;
    int h = t1 / DIM;

    const float* sS = pS + (size_t)b * NC * NV + v4;
    const float* sT = pT + (size_t)b * NC * NV + v4;
    const unsigned short* w0 = wm + (size_t)b * PADV;

    int off = (h + 1) * HS2 + (w + 1) * WS2 + (d + 8);
    ushort4 m1 = *(const ushort4*)(w0 + off);
    ushort4 m0 = *(const ushort4*)(w0 + off - HS2);      // halo slabs zeroed
    ushort4 m2 = *(const ushort4*)(w0 + off + HS2);

    f4 seS = {0, 0, 0, 0}, seT = {0, 0, 0, 0}, dot = {0, 0, 0, 0};
#pragma unroll
    for (int c = 0; c < NC; ++c) {
        f4 vs = __builtin_nontemporal_load((const f4*)(sS + (size_t)c * NV));
        f4 vt = *(const f4*)(sT + (size_t)c * NV);       // cached: L3-resident
        float e;
        seS.x += __expf(vs.x); e = __expf(vt.x); seT.x += e; dot.x += e * (vt.x - vs.x);
        seS.y += __expf(vs.y); e = __expf(vt.y); seT.y += e; dot.y += e * (vt.y - vs.y);
        seS.z += __expf(vs.z); e = __expf(vt.z); seT.z += e; dot.z += e * (vt.z - vs.z);
        seS.w += __expf(vs.w); e = __expf(vt.w); seT.w += e; dot.w += e * (vt.w - vs.w);
    }
    // pk = dot/seT + log(seS/seT) = fma(dot, r, log(seS*r)), r = 1/seT
    float pk[4];
    {
        float r;
        r = __builtin_amdgcn_rcpf(seT.x); pk[0] = fmaf(dot.x, r, __logf(seS.x * r));
        r = __builtin_amdgcn_rcpf(seT.y); pk[1] = fmaf(dot.y, r, __logf(seS.y * r));
        r = __builtin_amdgcn_rcpf(seT.z); pk[2] = fmaf(dot.z, r, __logf(seS.z * r));
        r = __builtin_amdgcn_rcpf(seT.w); pk[3] = fmaf(dot.w, r, __logf(seS.w * r));
    }

    unsigned mk[4];
    mk[0] = (unsigned)(m0.x | m1.x | m2.x);
    mk[1] = (unsigned)(m0.y | m1.y | m2.y);
    mk[2] = (unsigned)(m0.z | m1.z | m2.z);
    mk[3] = (unsigned)(m0.w | m1.w | m2.w);

    bool hwint = ((unsigned)(h - 1) <= 93u) && ((unsigned)(w - 1) <= 93u);
    float num[NC], cnt[NC];
#pragma unroll
    for (int c = 0; c < NC; ++c) { num[c] = 0.f; cnt[c] = 0.f; }
#pragma unroll
    for (int j = 0; j < 4; ++j) {
        unsigned m = mk[j];
        // fully-interior uniform 3x3x3 window -> box-sum==27 -> not boundary
        if (hwint && ((unsigned)(d + j - 1) <= 93u) && (m & (m - 1)) == 0u) m = 0u;
        float p = pk[j];
#pragma unroll
        for (int c = 0; c < NC; ++c) {
            float hit = (float)((m >> c) & 1u);
            num[c] = fmaf(hit, p, num[c]);
            cnt[c] += hit;
        }
    }

    // wave shfl reduction -> LDS -> global atomics (spread slots, 64B apart)
    __shared__ float snum[NC], scnt[NC];
    if (threadIdx.x < NC) { snum[threadIdx.x] = 0.f; scnt[threadIdx.x] = 0.f; }
    __syncthreads();
    int lane = threadIdx.x & 63;
#pragma unroll
    for (int c = 0; c < NC; ++c) {
        float s = num[c], n = cnt[c];
#pragma unroll
        for (int o = 32; o; o >>= 1) {
            s += __shfl_xor(s, o);
            n += __shfl_xor(n, o);
        }
        if (lane == 0) {
            atomicAdd(&snum[c], s);
            atomicAdd(&scnt[c], n);
        }
    }
    __syncthreads();
    if (threadIdx.x < NC) {
        atomicAdd(&acc[(b * NC + threadIdx.x) * 16], snum[threadIdx.x]);
        atomicAdd(&acc[(32 + b * NC + threadIdx.x) * 16], scnt[threadIdx.x]);
    }
}

// ---- Kernel C: finalize scalar ----
__global__ void finalize_kernel(const float* __restrict__ acc, float* __restrict__ out) {
    if (threadIdx.x == 0 && blockIdx.x == 0) {
        float s = 0.f;
        for (int i = 0; i < 2 * NC; ++i) {
            float n = acc[(32 + i) * 16];
            if (n > 0.f) s += acc[i * 16] / ((float)NC * n);
        }
        out[0] = s;
    }
}

extern "C" void kernel_launch(void* const* d_in, const int* in_sizes, int n_in,
                              void* d_out, int out_size, void* d_ws, size_t ws_size,
                              hipStream_t stream) {
    const float* preds_S = (const float*)d_in[0];
    const float* preds_T = (const float*)d_in[1];
    const float* outputs_T = (const float*)d_in[2];

    // ws layout: [4KB acc][wm slab]. No memset: every wm cell consumed is
    // written by argmax_or (valid region + distributed halo zero); acc is
    // zeroed in argmax_or block 0 each call.
    char* ws = (char*)d_ws;
    float* acc = (float*)ws;
    unsigned short* wm = (unsigned short*)(ws + 4096);

    argmax_or_kernel<<<384, 256, 0, stream>>>(outputs_T, wm, acc);
    boundary_kl_kernel<<<2 * (NV4 / 256), 256, 0, stream>>>(preds_S, preds_T, wm, acc);
    finalize_kernel<<<1, 64, 0, stream>>>(acc, (float*)d_out);
}

// Round 20
// 74.924 us; speedup vs baseline: 1.0467x; 1.0467x over previous
//
#include <hip/hip_runtime.h>

#define NC 14
#define DIM 96
#define NV (DIM*DIM*DIM)       // 884736
#define NV4 (NV/4)             // 221184
// padded mask volume: [ph 98][pw 98][pd 112], voxel (h,w,d) -> (h+1, w+1, d+8)
#define WS2 112
#define HS2 (112*98)           // 10976
#define PADV (112*98*98)       // 1075648 elements per batch

typedef float f4 __attribute__((ext_vector_type(4)));

// ---- Kernel A: fused argmax + (w,d) 3x3 window-OR, half-slice per block ----
// EXACT R13 version (~6us): cached outputs_T (L3-resident across replays),
// no halo-slab zeroing (R18/R19 showed the zeroing+uncond-load combo costs
// ~8us here regardless of distribution). Block 0 zeroes the accumulator.
__global__ void __launch_bounds__(256)
argmax_or_kernel(const float* __restrict__ outT, unsigned short* __restrict__ wm,
                 float* __restrict__ acc) {
    if (blockIdx.x == 0 && threadIdx.x < 64) acc[threadIdx.x * 16] = 0.f;

    const int half = blockIdx.x & 1;                // row-half of the slice
    const int b = (blockIdx.x >> 1) & 1;
    const int ph = (blockIdx.x >> 2) + 1;           // 1..96
    const int h = ph - 1;
    const int r0 = half * 48;                       // pw = r0 + lr

    __shared__ unsigned short tile[50][WS2];        // 11,200 B
    for (int i = threadIdx.x; i < 50 * WS2 / 2; i += 256)
        ((unsigned*)tile)[i] = 0u;                  // halo rows/cols stay 0
    __syncthreads();

    // argmax for valid rows: half=0 -> lr 1..49 (pw 1..49), half=1 -> lr 0..48
    {
        const int lr0 = (half == 0) ? 1 : 0;
        const float* base = outT + (size_t)b * NC * NV + (size_t)h * (DIM * DIM);
        for (int i = threadIdx.x; i < 49 * 24; i += 256) {
            int lr = lr0 + i / 24;
            int d = (i % 24) * 4;
            int w = r0 + lr - 1;                    // global w = pw-1
            const float* po = base + w * DIM + d;
            f4 best = *(const f4*)po;
            int b0 = 0, b1 = 0, b2 = 0, b3 = 0;
#pragma unroll
            for (int c = 1; c < NC; ++c) {
                f4 v = *(const f4*)(po + (size_t)c * NV);
                if (v.x > best.x) { best.x = v.x; b0 = c; }
                if (v.y > best.y) { best.y = v.y; b1 = c; }
                if (v.z > best.z) { best.z = v.z; b2 = c; }
                if (v.w > best.w) { best.w = v.w; b3 = c; }
            }
            ushort4 bits;
            bits.x = (unsigned short)(1u << b0);
            bits.y = (unsigned short)(1u << b1);
            bits.z = (unsigned short)(1u << b2);
            bits.w = (unsigned short)(1u << b3);
            *(ushort4*)&tile[lr][8 + d] = bits;
        }
    }
    __syncthreads();

    // 3x3 (w,d) window-OR: 48 output rows (local 1..48) x 12 chunks of 8
    unsigned short* dst = wm + (size_t)b * PADV + ph * HS2;
    for (int i = threadIdx.x; i < 48 * 12; i += 256) {
        int lr = 1 + i / 12;
        int pd0 = 8 + (i % 12) * 8;
        uint4 A = *(const uint4*)&tile[lr - 1][pd0];
        uint4 B = *(const uint4*)&tile[lr][pd0];
        uint4 C = *(const uint4*)&tile[lr + 1][pd0];
        unsigned lft = (unsigned)tile[lr - 1][pd0 - 1] | (unsigned)tile[lr][pd0 - 1] |
                       (unsigned)tile[lr + 1][pd0 - 1];
        unsigned rgt = (unsigned)tile[lr - 1][pd0 + 8] | (unsigned)tile[lr][pd0 + 8] |
                       (unsigned)tile[lr + 1][pd0 + 8];
        uint4 W;
        W.x = A.x | B.x | C.x;
        W.y = A.y | B.y | C.y;
        W.z = A.z | B.z | C.z;
        W.w = A.w | B.w | C.w;
        unsigned x[10];
        x[0] = lft;
        x[1] = W.x & 0xFFFFu; x[2] = W.x >> 16;
        x[3] = W.y & 0xFFFFu; x[4] = W.y >> 16;
        x[5] = W.z & 0xFFFFu; x[6] = W.z >> 16;
        x[7] = W.w & 0xFFFFu; x[8] = W.w >> 16;
        x[9] = rgt;
        unsigned r[8];
#pragma unroll
        for (int j = 0; j < 8; ++j) r[j] = x[j] | x[j + 1] | x[j + 2];
        uint4 out;
        out.x = r[0] | (r[1] << 16);
        out.y = r[2] | (r[3] << 16);
        out.z = r[4] | (r[5] << 16);
        out.w = r[6] | (r[7] << 16);
        *(uint4*)(dst + (r0 + lr) * WS2 + pd0) = out;
    }
}

// ---- Kernel B: h-OR (edge-clamped) + KL + accumulation, 4 voxels/thread ----
// EXACT R13 version + ONE change: rcp+single-log pk tail (validated in
// R17-R19: bkl 68 -> ~63us, no spill). Conditional m0/m2 loads (no halo
// zeroing). CACHE PARTITION: outputs_T + preds_T L3-resident (cached);
// preds_S NON-TEMPORAL. Natural register pressure only (R8/R15: forced
// wave minimums spill 180-214MB, 2x slower).
__global__ void __launch_bounds__(256)
boundary_kl_kernel(const float* __restrict__ pS, const float* __restrict__ pT,
                   const unsigned short* __restrict__ wm,
                   float* __restrict__ acc) {
    const int b = blockIdx.x & 1;
    int tid4 = (blockIdx.x >> 1) * 256 + threadIdx.x;    // < NV4 exactly
    int v4 = tid4 * 4;
    int d = v4 % DIM;                                    // multiple of 4
    int t1 = v4 / DIM;
    int w = t1 % DIM;
    int h = t1 / DIM;

    const float* sS = pS + (size_t)b * NC * NV + v4;
    const float* sT = pT + (size_t)b * NC * NV + v4;
    const unsigned short* w0 = wm + (size_t)b * PADV;

    int off = (h + 1) * HS2 + (w + 1) * WS2 + (d + 8);
    ushort4 m1 = *(const ushort4*)(w0 + off);
    ushort4 m0 = {0, 0, 0, 0}, m2 = {0, 0, 0, 0};
    if (h > 0)  m0 = *(const ushort4*)(w0 + off - HS2);  // h-1 slab (0 at edge)
    if (h < 95) m2 = *(const ushort4*)(w0 + off + HS2);  // h+1 slab

    f4 seS = {0, 0, 0, 0}, seT = {0, 0, 0, 0}, dot = {0, 0, 0, 0};
#pragma unroll
    for (int c = 0; c < NC; ++c) {
        f4 vs = __builtin_nontemporal_load((const f4*)(sS + (size_t)c * NV));
        f4 vt = *(const f4*)(sT + (size_t)c * NV);       // cached: L3-resident
        float e;
        seS.x += __expf(vs.x); e = __expf(vt.x); seT.x += e; dot.x += e * (vt.x - vs.x);
        seS.y += __expf(vs.y); e = __expf(vt.y); seT.y += e; dot.y += e * (vt.y - vs.y);
        seS.z += __expf(vs.z); e = __expf(vt.z); seT.z += e; dot.z += e * (vt.z - vs.z);
        seS.w += __expf(vs.w); e = __expf(vt.w); seT.w += e; dot.w += e * (vt.w - vs.w);
    }
    // pk = dot/seT + log(seS/seT) = fma(dot, r, log(seS*r)), r = 1/seT
    float pk[4];
    {
        float r;
        r = __builtin_amdgcn_rcpf(seT.x); pk[0] = fmaf(dot.x, r, __logf(seS.x * r));
        r = __builtin_amdgcn_rcpf(seT.y); pk[1] = fmaf(dot.y, r, __logf(seS.y * r));
        r = __builtin_amdgcn_rcpf(seT.z); pk[2] = fmaf(dot.z, r, __logf(seS.z * r));
        r = __builtin_amdgcn_rcpf(seT.w); pk[3] = fmaf(dot.w, r, __logf(seS.w * r));
    }

    unsigned mk[4];
    mk[0] = (unsigned)(m0.x | m1.x | m2.x);
    mk[1] = (unsigned)(m0.y | m1.y | m2.y);
    mk[2] = (unsigned)(m0.z | m1.z | m2.z);
    mk[3] = (unsigned)(m0.w | m1.w | m2.w);

    bool hwint = ((unsigned)(h - 1) <= 93u) && ((unsigned)(w - 1) <= 93u);
    float num[NC], cnt[NC];
#pragma unroll
    for (int c = 0; c < NC; ++c) { num[c] = 0.f; cnt[c] = 0.f; }
#pragma unroll
    for (int j = 0; j < 4; ++j) {
        unsigned m = mk[j];
        // fully-interior uniform 3x3x3 window -> box-sum==27 -> not boundary
        if (hwint && ((unsigned)(d + j - 1) <= 93u) && (m & (m - 1)) == 0u) m = 0u;
        float p = pk[j];
#pragma unroll
        for (int c = 0; c < NC; ++c) {
            float hit = (float)((m >> c) & 1u);
            num[c] = fmaf(hit, p, num[c]);
            cnt[c] += hit;
        }
    }

    // wave shfl reduction -> LDS -> global atomics (spread slots, 64B apart)
    __shared__ float snum[NC], scnt[NC];
    if (threadIdx.x < NC) { snum[threadIdx.x] = 0.f; scnt[threadIdx.x] = 0.f; }
    __syncthreads();
    int lane = threadIdx.x & 63;
#pragma unroll
    for (int c = 0; c < NC; ++c) {
        float s = num[c], n = cnt[c];
#pragma unroll
        for (int o = 32; o; o >>= 1) {
            s += __shfl_xor(s, o);
            n += __shfl_xor(n, o);
        }
        if (lane == 0) {
            atomicAdd(&snum[c], s);
            atomicAdd(&scnt[c], n);
        }
    }
    __syncthreads();
    if (threadIdx.x < NC) {
        atomicAdd(&acc[(b * NC + threadIdx.x) * 16], snum[threadIdx.x]);
        atomicAdd(&acc[(32 + b * NC + threadIdx.x) * 16], scnt[threadIdx.x]);
    }
}

// ---- Kernel C: finalize scalar ----
__global__ void finalize_kernel(const float* __restrict__ acc, float* __restrict__ out) {
    if (threadIdx.x == 0 && blockIdx.x == 0) {
        float s = 0.f;
        for (int i = 0; i < 2 * NC; ++i) {
            float n = acc[(32 + i) * 16];
            if (n > 0.f) s += acc[i * 16] / ((float)NC * n);
        }
        out[0] = s;
    }
}

extern "C" void kernel_launch(void* const* d_in, const int* in_sizes, int n_in,
                              void* d_out, int out_size, void* d_ws, size_t ws_size,
                              hipStream_t stream) {
    const float* preds_S = (const float*)d_in[0];
    const float* preds_T = (const float*)d_in[1];
    const float* outputs_T = (const float*)d_in[2];

    // ws layout: [4KB acc][wm slab]. No memset: every wm cell consumed is
    // written by argmax_or (valid region) or edge-clamped; acc is zeroed in
    // argmax_or block 0 each call.
    char* ws = (char*)d_ws;
    float* acc = (float*)ws;
    unsigned short* wm = (unsigned short*)(ws + 4096);

    argmax_or_kernel<<<384, 256, 0, stream>>>(outputs_T, wm, acc);
    boundary_kl_kernel<<<2 * (NV4 / 256), 256, 0, stream>>>(preds_S, preds_T, wm, acc);
    finalize_kernel<<<1, 64, 0, stream>>>(acc, (float*)d_out);
}